// Round 5
// baseline (404.108 us; speedup 1.0000x reference)
//
#include <hip/hip_runtime.h>

// Problem constants (B=32, T=4096, D=256, A=128, window=64)
#define TT 4096
#define DD 256
#define AA 128
#define WIN 64

typedef short bf16x8 __attribute__((ext_vector_type(8)));
typedef float f32x4 __attribute__((ext_vector_type(4)));
typedef unsigned int u32x4 __attribute__((ext_vector_type(4)));

__device__ __forceinline__ unsigned short f2bf(float f) {
    unsigned int u = __builtin_bit_cast(unsigned int, f);
    u += 0x7FFFu + ((u >> 16) & 1u);   // RTNE
    return (unsigned short)(u >> 16);
}

// packed f32x2 -> bf16x2 (RTNE), element 0 = lo
__device__ __forceinline__ unsigned int cvt_pk_bf16(float lo, float hi) {
    unsigned int r;
    asm("v_cvt_pk_bf16_f32 %0, %1, %2" : "=v"(r) : "v"(lo), "v"(hi));
    return r;
}

// ---------------- prep: Wp fp32 -> bf16 (64 KiB, L2-resident) ----------------
__global__ __launch_bounds__(256) void prep_wp(const float* __restrict__ Wp,
                                               unsigned short* __restrict__ wpb) {
    int i = blockIdx.x * 256 + threadIdx.x;   // 32768 total
    wpb[i] = f2bf(Wp[i]);
}

// ---------------- fused v5: gate + stream, NO x staging ----------------------
// A-fragments load straight from global (16 rows x 128 B wave footprint per
// k0 — coalesces fine); stream re-reads x from global: same tile is L1-warm
// (just read by MFMA this iteration), t-64 tile L2-warm. LDS = gbuf+psum only
// (~2 KiB) -> 2 blocks/CU, 8 waves/CU; 2 raw barriers/iter; no vmcnt drains.
#define SROWS 32
#define TC    256
#define NU    ((TC + WIN) / SROWS)   // 10 subtiles incl. 2 halo
#define NCHK  (TT / TC)              // 16 chunks per batch row

__global__ __launch_bounds__(256, 2) void fused_kernel(
        const float* __restrict__ x, const unsigned short* __restrict__ wpb,
        const float* __restrict__ bp, const float* __restrict__ Wg,
        float* __restrict__ out) {
    __shared__ float gbuf[4][SROWS];   // g ring, slot u&3 = subtile u
    __shared__ float psum[4][SROWS];   // per-wave gate partials
    const int tid  = threadIdx.x;
    const int lane = tid & 63;
    const int wave = tid >> 6;
    const int quad = lane >> 4;
    const int nrow = lane & 15;
    const int b     = blockIdx.x >> 4;          // NCHK = 16
    const int chunk = blockIdx.x & (NCHK - 1);
    const long t0   = (long)chunk * TC;
    const float* xb = x   + (size_t)b * TT * DD;
    float*       ob = out + (size_t)b * TT * DD;

    // B fragments: wave covers n in [wave*32, wave*32+32)
    bf16x8 bfrag[2][8];
    float bpv[2], wgv[2];
#pragma unroll
    for (int nt = 0; nt < 2; ++nt) {
        int n = wave * 32 + nt * 16 + nrow;
        bpv[nt] = bp[n];
        wgv[nt] = Wg[n];
#pragma unroll
        for (int k0 = 0; k0 < 8; ++k0)
            bfrag[nt][k0] = *reinterpret_cast<const bf16x8*>(
                wpb + n * DD + k0 * 32 + quad * 8);
    }

    float S = 0.f, Sg = 0.f;   // windowed recurrence state (thread owns col tid)

    for (int u = 0; u < NU; ++u) {
        const long rbase = t0 - WIN + (long)u * SROWS;

        // ---- phase 1: gate MFMA, A-fragments direct from global ----
        long R0 = rbase + nrow;          // mt=0 row
        long R1 = rbase + 16 + nrow;     // mt=1 row
        if (rbase < 0) {                 // first-chunk halo: clamp (g=0 kills it)
            R0 = R0 < 0 ? 0 : R0;
            R1 = R1 < 0 ? 0 : R1;
        }
        const float* rp0 = xb + R0 * DD + quad * 8;
        const float* rp1 = xb + R1 * DD + quad * 8;

        f32x4 acc[2][2];
#pragma unroll
        for (int mt = 0; mt < 2; ++mt)
#pragma unroll
            for (int nt = 0; nt < 2; ++nt)
                acc[mt][nt] = (f32x4){0.f, 0.f, 0.f, 0.f};

#pragma unroll
        for (int k0 = 0; k0 < 8; ++k0) {
            float4 a0 = *reinterpret_cast<const float4*>(rp0 + k0 * 32);
            float4 a1 = *reinterpret_cast<const float4*>(rp0 + k0 * 32 + 4);
            float4 c0 = *reinterpret_cast<const float4*>(rp1 + k0 * 32);
            float4 c1 = *reinterpret_cast<const float4*>(rp1 + k0 * 32 + 4);
            u32x4 w0, w1;
            w0.x = cvt_pk_bf16(a0.x, a0.y);
            w0.y = cvt_pk_bf16(a0.z, a0.w);
            w0.z = cvt_pk_bf16(a1.x, a1.y);
            w0.w = cvt_pk_bf16(a1.z, a1.w);
            w1.x = cvt_pk_bf16(c0.x, c0.y);
            w1.y = cvt_pk_bf16(c0.z, c0.w);
            w1.z = cvt_pk_bf16(c1.x, c1.y);
            w1.w = cvt_pk_bf16(c1.z, c1.w);
            bf16x8 af0 = __builtin_bit_cast(bf16x8, w0);
            bf16x8 af1 = __builtin_bit_cast(bf16x8, w1);
            acc[0][0] = __builtin_amdgcn_mfma_f32_16x16x32_bf16(af0, bfrag[0][k0], acc[0][0], 0, 0, 0);
            acc[0][1] = __builtin_amdgcn_mfma_f32_16x16x32_bf16(af0, bfrag[1][k0], acc[0][1], 0, 0, 0);
            acc[1][0] = __builtin_amdgcn_mfma_f32_16x16x32_bf16(af1, bfrag[0][k0], acc[1][0], 0, 0, 0);
            acc[1][1] = __builtin_amdgcn_mfma_f32_16x16x32_bf16(af1, bfrag[1][k0], acc[1][1], 0, 0, 0);
        }

        // epilogue: tanh -> *Wg -> partial row sums (this wave's 32 n-cols)
        float p[2][4];
#pragma unroll
        for (int mt = 0; mt < 2; ++mt)
#pragma unroll
            for (int r = 0; r < 4; ++r) p[mt][r] = 0.f;
#pragma unroll
        for (int nt = 0; nt < 2; ++nt) {
#pragma unroll
            for (int mt = 0; mt < 2; ++mt) {
#pragma unroll
                for (int r = 0; r < 4; ++r) {
                    float pre = acc[mt][nt][r] + bpv[nt];
                    float e  = __expf(2.0f * pre);
                    float th = 1.0f - 2.0f * __builtin_amdgcn_rcpf(e + 1.0f);
                    p[mt][r] += th * wgv[nt];
                }
            }
        }
#pragma unroll
        for (int off = 1; off <= 8; off <<= 1)
#pragma unroll
            for (int mt = 0; mt < 2; ++mt)
#pragma unroll
                for (int r = 0; r < 4; ++r)
                    p[mt][r] += __shfl_xor(p[mt][r], off, 64);
        if (nrow == 0) {
#pragma unroll
            for (int mt = 0; mt < 2; ++mt)
#pragma unroll
                for (int r = 0; r < 4; ++r)
                    psum[wave][mt * 16 + quad * 4 + r] = p[mt][r];
        }

        asm volatile("s_waitcnt lgkmcnt(0)" ::: "memory");
        __builtin_amdgcn_sched_barrier(0);
        __builtin_amdgcn_s_barrier();            // psum visible
        __builtin_amdgcn_sched_barrier(0);

        // ---- phase 3: finalize g[u] into the ring ----
        if (tid < SROWS) {
            float ssum = psum[0][tid] + psum[1][tid] + psum[2][tid] + psum[3][tid];
            float gg = __builtin_amdgcn_rcpf(1.0f + __expf(-ssum));
            gbuf[u & 3][tid] = (rbase + tid < 0) ? 0.f : gg;
        }
        asm volatile("s_waitcnt lgkmcnt(0)" ::: "memory");
        __builtin_amdgcn_sched_barrier(0);
        __builtin_amdgcn_s_barrier();            // gbuf visible; psum reusable
        __builtin_amdgcn_sched_barrier(0);

        // ---- phase 5: windowed recurrence, thread owns column d = tid ----
        if (u >= 2) {
            const float* gn = gbuf[u & 3];
            const float* go = gbuf[(u + 2) & 3];     // == (u-2)&3
            const long tb = t0 + (long)(u - 2) * SROWS;
#pragma unroll 16
            for (int tt = 0; tt < SROWS; ++tt) {
                long tn = tb + tt;
                long to = tn - WIN;
                to = to < 0 ? 0 : to;                // gold=0 there anyway
                float gnew = gn[tt];
                float gold = go[tt];
                float xn = xb[tn * DD + tid];
                float xo = xb[to * DD + tid];
                S  += gnew * xn - gold * xo;
                Sg += gnew - gold;
                ob[tn * DD + tid] = S * __builtin_amdgcn_rcpf(Sg);
            }
        } else {
            // halo accumulation: build S,Sg over [t0-64, t0)
            const float* gn = gbuf[u & 3];
#pragma unroll 16
            for (int tt = 0; tt < SROWS; ++tt) {
                long rn = rbase + tt;
                rn = rn < 0 ? 0 : rn;
                float gnew = gn[tt];
                S  += gnew * xb[rn * DD + tid];
                Sg += gnew;
            }
        }
        // no third barrier needed: next iter's first shared write (psum) is
        // ordered after this iter's barrier B for every wave.
    }
}

extern "C" void kernel_launch(void* const* d_in, const int* in_sizes, int n_in,
                              void* d_out, int out_size, void* d_ws, size_t ws_size,
                              hipStream_t stream) {
    const float* x  = (const float*)d_in[0];
    const float* Wp = (const float*)d_in[1];
    const float* bp = (const float*)d_in[2];
    const float* Wg = (const float*)d_in[3];
    float* out = (float*)d_out;

    // ws layout: [0,64K) Wp bf16
    unsigned short* wpb = (unsigned short*)d_ws;

    prep_wp<<<AA * DD / 256, 256, 0, stream>>>(Wp, wpb);
    fused_kernel<<<32 * NCHK, 256, 0, stream>>>(x, wpb, bp, Wg, out);
}

// Round 7
// 270.716 us; speedup vs baseline: 1.4927x; 1.4927x over previous
//
#include <hip/hip_runtime.h>

// Problem constants (B=32, T=4096, D=256, A=128, window=64)
#define TT 4096
#define DD 256
#define AA 128
#define WIN 64

typedef short bf16x8 __attribute__((ext_vector_type(8)));
typedef float f32x4 __attribute__((ext_vector_type(4)));
typedef unsigned int u32x4 __attribute__((ext_vector_type(4)));

__device__ __forceinline__ unsigned short f2bf(float f) {
    unsigned int u = __builtin_bit_cast(unsigned int, f);
    u += 0x7FFFu + ((u >> 16) & 1u);   // RTNE
    return (unsigned short)(u >> 16);
}

// packed f32x2 -> bf16x2 (RTNE), element 0 = lo
__device__ __forceinline__ unsigned int cvt_pk_bf16(float lo, float hi) {
    unsigned int r;
    asm("v_cvt_pk_bf16_f32 %0, %1, %2" : "=v"(r) : "v"(lo), "v"(hi));
    return r;
}

// ---------------- prep: Wp fp32 -> bf16 (64 KiB, L2-resident) ----------------
__global__ __launch_bounds__(256) void prep_wp(const float* __restrict__ Wp,
                                               unsigned short* __restrict__ wpb) {
    int i = blockIdx.x * 256 + threadIdx.x;   // 32768 total
    wpb[i] = f2bf(Wp[i]);
}

// ---------------- fused v6: gate + stream, 2-deep ring, 2 blocks/CU ----------
// MFMA A-fragments from a 2-deep fp32 LDS ring (global_load_lds dwordx4,
// XOR-swizzled source / linear dest). Stream reads x from GLOBAL (rows were
// DMA-read <=2 subtiles ago -> L2-hit, HBM still x-once). Stream lags gate by
// one subtile so gbuf needs no extra barrier. 66 KiB LDS -> 2 blocks/CU;
// 2 raw barriers/iter; prefetch in flight across the whole body (vmcnt(8)).
#define SROWS 32
#define TC    256
#define NU    ((TC + WIN) / SROWS)   // 10 subtiles incl. 2 halo
#define NCHK  (TT / TC)              // 16 chunks per batch row

__global__ __launch_bounds__(256, 2) void fused_kernel(
        const float* __restrict__ x, const unsigned short* __restrict__ wpb,
        const float* __restrict__ bp, const float* __restrict__ Wg,
        float* __restrict__ out) {
    __shared__ __align__(16) float xs[2][SROWS * DD];   // 64 KiB ring
    __shared__ float gbuf[4][SROWS];   // g ring, slot s&3 = subtile s
    __shared__ float psum[4][SROWS];   // per-wave gate partials
    const int tid  = threadIdx.x;
    const int lane = tid & 63;
    const int wave = tid >> 6;
    const int quad = lane >> 4;
    const int nrow = lane & 15;
    const int sw   = nrow & 7;          // row&7 == nrow&7 (mt*16 ≡ 0 mod 8)
    const int b     = blockIdx.x >> 4;          // NCHK = 16
    const int chunk = blockIdx.x & (NCHK - 1);
    const long t0   = (long)chunk * TC;
    const float* xb = x   + (size_t)b * TT * DD;
    float*       ob = out + (size_t)b * TT * DD;

    // B fragments: wave covers n in [wave*32, wave*32+32)
    bf16x8 bfrag[2][8];
    float bpv[2], wgv[2];
#pragma unroll
    for (int nt = 0; nt < 2; ++nt) {
        int n = wave * 32 + nt * 16 + nrow;
        bpv[nt] = bp[n];
        wgv[nt] = Wg[n];
#pragma unroll
        for (int k0 = 0; k0 < 8; ++k0)
            bfrag[nt][k0] = *reinterpret_cast<const bf16x8*>(
                wpb + n * DD + k0 * 32 + quad * 8);
    }

    // stage subtile su into ring slot su&1: 8 global_load_lds dwordx4 / wave.
    // LDS dest linear (row r, granule lane); global source granule lane^(r&7),
    // so a read of granule gidx comes from slot gidx^(r&7).
    auto stage = [&](int su) {
        const int nb = su & 1;
        const long r0 = t0 - WIN + (long)su * SROWS;
#pragma unroll
        for (int j = 0; j < 8; ++j) {
            int r = wave * 8 + j;
            long row = r0 + r;
            row = row < 0 ? 0 : row;          // t0=0 halo clamp (g=0 kills it)
            const float* gp = xb + row * DD + ((lane ^ (r & 7)) << 2);
            __builtin_amdgcn_global_load_lds(
                (const __attribute__((address_space(1))) void*)gp,
                (__attribute__((address_space(3))) void*)&xs[nb][r * DD],
                16, 0, 0);
        }
    };

    float S = 0.f, Sg = 0.f;   // windowed recurrence state (thread owns col tid)

    stage(0);

    for (int u = 0; u <= NU; ++u) {
        if (u + 1 < NU) stage(u + 1);        // prefetch, in flight all body

        // wait: stage(u) complete (leave stage(u+1)'s 8 loads in flight);
        // lgkmcnt(0) publishes last iter's gbuf ds_writes before the barrier.
        if (u + 1 < NU) asm volatile("s_waitcnt vmcnt(8) lgkmcnt(0)" ::: "memory");
        else            asm volatile("s_waitcnt vmcnt(0) lgkmcnt(0)" ::: "memory");
        __builtin_amdgcn_sched_barrier(0);
        __builtin_amdgcn_s_barrier();        // stage(u) visible to all waves
        __builtin_amdgcn_sched_barrier(0);

        if (u < NU) {
            // ---- gate MFMA on xs[u&1] ----
            const float* buf = xs[u & 1];
            f32x4 acc[2][2];
#pragma unroll
            for (int mt = 0; mt < 2; ++mt)
#pragma unroll
                for (int nt = 0; nt < 2; ++nt)
                    acc[mt][nt] = (f32x4){0.f, 0.f, 0.f, 0.f};
#pragma unroll
            for (int k0 = 0; k0 < 8; ++k0) {
#pragma unroll
                for (int mt = 0; mt < 2; ++mt) {
                    const float* rowp = buf + (mt * 16 + nrow) * DD;
                    const int gidx = quad * 2 + k0 * 8;
                    float4 f0 = *reinterpret_cast<const float4*>(rowp + (((gidx)     ^ sw) << 2));
                    float4 f1 = *reinterpret_cast<const float4*>(rowp + (((gidx + 1) ^ sw) << 2));
                    u32x4 w;
                    w.x = cvt_pk_bf16(f0.x, f0.y);
                    w.y = cvt_pk_bf16(f0.z, f0.w);
                    w.z = cvt_pk_bf16(f1.x, f1.y);
                    w.w = cvt_pk_bf16(f1.z, f1.w);
                    bf16x8 af = __builtin_bit_cast(bf16x8, w);
                    acc[mt][0] = __builtin_amdgcn_mfma_f32_16x16x32_bf16(af, bfrag[0][k0], acc[mt][0], 0, 0, 0);
                    acc[mt][1] = __builtin_amdgcn_mfma_f32_16x16x32_bf16(af, bfrag[1][k0], acc[mt][1], 0, 0, 0);
                }
            }
            // epilogue: tanh -> *Wg -> partial row sums
            float p[2][4];
#pragma unroll
            for (int mt = 0; mt < 2; ++mt)
#pragma unroll
                for (int r = 0; r < 4; ++r) p[mt][r] = 0.f;
#pragma unroll
            for (int nt = 0; nt < 2; ++nt) {
#pragma unroll
                for (int mt = 0; mt < 2; ++mt) {
#pragma unroll
                    for (int r = 0; r < 4; ++r) {
                        float pre = acc[mt][nt][r] + bpv[nt];
                        float e  = __expf(2.0f * pre);
                        float th = 1.0f - 2.0f * __builtin_amdgcn_rcpf(e + 1.0f);
                        p[mt][r] += th * wgv[nt];
                    }
                }
            }
#pragma unroll
            for (int off = 1; off <= 8; off <<= 1)
#pragma unroll
                for (int mt = 0; mt < 2; ++mt)
#pragma unroll
                    for (int r = 0; r < 4; ++r)
                        p[mt][r] += __shfl_xor(p[mt][r], off, 64);
            if (nrow == 0) {
#pragma unroll
                for (int mt = 0; mt < 2; ++mt)
#pragma unroll
                    for (int r = 0; r < 4; ++r)
                        psum[wave][mt * 16 + quad * 4 + r] = p[mt][r];
            }
        }

        asm volatile("s_waitcnt lgkmcnt(0)" ::: "memory");
        __builtin_amdgcn_sched_barrier(0);
        __builtin_amdgcn_s_barrier();        // psum visible; xs slot (u+1)&1 free
        __builtin_amdgcn_sched_barrier(0);

        // ---- finalize g[u] into the ring ----
        if (u < NU && tid < SROWS) {
            float ssum = psum[0][tid] + psum[1][tid] + psum[2][tid] + psum[3][tid];
            float gg = __builtin_amdgcn_rcpf(1.0f + __expf(-ssum));
            long row = t0 - WIN + (long)u * SROWS + tid;
            gbuf[u & 3][tid] = (row < 0) ? 0.f : gg;
        }

        // ---- stream: output subtile w = u-1 (lagged; gbuf[w] barrier-safe) ----
        if (u >= 1) {
            const int w = u - 1;
            const float* gn = gbuf[w & 3];
            const long rb = t0 - WIN + (long)w * SROWS;   // row base of subtile w
            if (w >= 2) {
                const float* go = gbuf[(w + 2) & 3];      // == (w-2)&3
#pragma unroll 16
                for (int tt = 0; tt < SROWS; ++tt) {
                    long tn = rb + tt;                    // >= t0
                    long to = tn - WIN;
                    to = to < 0 ? 0 : to;                 // gold=0 there anyway
                    float gnew = gn[tt];
                    float gold = go[tt];
                    float xn = xb[tn * DD + tid];         // L2-warm (DMA'd iter u-1)
                    float xo = xb[to * DD + tid];         // L2-warm (DMA'd iter u-3)
                    S  += gnew * xn - gold * xo;
                    Sg += gnew - gold;
                    ob[tn * DD + tid] = S * __builtin_amdgcn_rcpf(Sg);
                }
            } else {
                // halo accumulation: build S,Sg over [t0-64, t0)
#pragma unroll 16
                for (int tt = 0; tt < SROWS; ++tt) {
                    long rn = rb + tt;
                    rn = rn < 0 ? 0 : rn;
                    float gnew = gn[tt];
                    S  += gnew * xb[rn * DD + tid];
                    Sg += gnew;
                }
            }
        }
        // next iter's barrier1 (with lgkmcnt(0)) publishes this iter's gbuf
        // write; xs slot reuse is fenced by barrier2 above.
    }
}

extern "C" void kernel_launch(void* const* d_in, const int* in_sizes, int n_in,
                              void* d_out, int out_size, void* d_ws, size_t ws_size,
                              hipStream_t stream) {
    const float* x  = (const float*)d_in[0];
    const float* Wp = (const float*)d_in[1];
    const float* bp = (const float*)d_in[2];
    const float* Wg = (const float*)d_in[3];
    float* out = (float*)d_out;

    // ws layout: [0,64K) Wp bf16
    unsigned short* wpb = (unsigned short*)d_ws;

    prep_wp<<<AA * DD / 256, 256, 0, stream>>>(Wp, wpb);
    fused_kernel<<<32 * NCHK, 256, 0, stream>>>(x, wpb, bp, Wg, out);
}